// Round 6
// baseline (273.295 us; speedup 1.0000x reference)
//
#include <hip/hip_runtime.h>

// CSR SpMV: y[r] = sum_{j in [ro[r], ro[r+1])} sx[j] * x[sel[j]]
// NNZ = 32M, ROWS = 1M (+1 offsets), COLS = 1M.
//
// R6 vs R5 (259us, third neutral microarch tweak, VGPR stuck at 28):
// VGPR=28 proves the compiler never held 16 gather results + addresses live
// -> per-wave MLP never rose. Fix: gather x via __builtin_amdgcn_global_load_lds
// (per-lane global source, LDS destination, ZERO dest VGPRs, vmcnt-tracked).
// Each lane issues 16 gathers back-to-back into a per-wave LDS slab, then the
// sx stream loads, then one __syncthreads (drains vmcnt -> slab valid), then
// conflict-free ds_read consumption fused into the row-walk.
// sro cache shrunk to 1536 entries so LDS/block = 22.5KB -> 7 blocks/CU.

constexpr int ITEMS     = 16;              // nnz per thread
constexpr int BLOCK     = 256;
constexpr int WAVES     = BLOCK / 64;
constexpr int CHUNK_NNZ = BLOCK * ITEMS;   // 4096 nnz per block
constexpr int SRO_CAP   = 1536;            // LDS row-offset cache (6 KB)

typedef float f32x4 __attribute__((ext_vector_type(4)));
typedef int   i32x4 __attribute__((ext_vector_type(4)));

__device__ __forceinline__ void gather_to_lds(const float* g, void* lds) {
    __builtin_amdgcn_global_load_lds(
        (const __attribute__((address_space(1))) void*)g,
        (__attribute__((address_space(3))) void*)lds,
        4, 0, 0);
}

__global__ __launch_bounds__(256) void zero_out(float* __restrict__ y, int n) {
    int i = blockIdx.x * blockDim.x + threadIdx.x;
    if (i < n) y[i] = 0.0f;
}

// upper_bound over ro[1..num_rows], returns row r with ro[r] <= key < ro[r+1]
__device__ __forceinline__ int row_of(const int* __restrict__ ro,
                                      int num_rows, int key) {
    int left = 1, right = num_rows;
    while (left < right) {
        int mid = (left + right) >> 1;
        if (ro[mid] <= key) left = mid + 1; else right = mid;
    }
    return left - 1;
}

__global__ __launch_bounds__(BLOCK) void spmv_chunk(
    const float* __restrict__ sx,
    const float* __restrict__ x,
    const int*   __restrict__ sel,
    const int*   __restrict__ ro,   // length num_rows+1, ro[0]=0, ro[nr]=nnz
    float*       __restrict__ y,
    int nnz, int num_rows)
{
    __shared__ int   sro[SRO_CAP];
    __shared__ float slab[WAVES][ITEMS][64];   // 16 KB gather landing zone
    __shared__ int   s_lo, s_hi;

    const int lane = threadIdx.x & 63;
    const int wid  = threadIdx.x >> 6;

    const int b  = blockIdx.x;
    const int B0 = b * CHUNK_NNZ;
    const int B1 = min(nnz, B0 + CHUNK_NNZ);

    if (threadIdx.x == 0)         s_lo = row_of(ro, num_rows, B0);
    if (threadIdx.x == BLOCK - 1) s_hi = row_of(ro, num_rows, B1 - 1);
    __syncthreads();

    const int lo = s_lo;
    const int n  = s_hi + 2 - lo;        // cache ro[lo .. hi+1], n entries
    const bool use_lds = (n <= SRO_CAP);
    if (use_lds) {
        for (int i = threadIdx.x; i < n; i += BLOCK) sro[i] = ro[lo + i];
    }
    __syncthreads();

    const int  j0     = (b * BLOCK + threadIdx.x) * ITEMS;
    const bool active = (j0 < nnz);      // NNZ%16==0 -> active threads have
                                         // full 16-item chunks. No early
                                         // return: barriers below need all.

    if (use_lds) {
        int r_local = 0, row_end = 0;
        f32x4 s[ITEMS / 4];

        if (active) {
            // Phase 0: row start via LDS binary search
            int left = 1, right = n - 1;
            while (left < right) {
                int mid = (left + right) >> 1;
                if (sro[mid] <= j0) left = mid + 1; else right = mid;
            }
            r_local = left - 1;
            row_end = sro[r_local + 1];

            // Phase 1a: load all 16 indices (nt), issue 16 LDS-gathers.
            // global_load_lds has NO dest VGPR -> nothing stops back-to-back
            // issue; 16 outstanding VMEM/wave guaranteed.
            i32x4 c[ITEMS / 4];
            #pragma unroll
            for (int v = 0; v < ITEMS / 4; ++v) {
                c[v] = __builtin_nontemporal_load(
                           reinterpret_cast<const i32x4*>(sel + j0) + v);
            }
            #pragma unroll
            for (int v = 0; v < ITEMS / 4; ++v) {
                #pragma unroll
                for (int k = 0; k < 4; ++k) {
                    // lane i's value lands at slab[wid][v*4+k][i]
                    gather_to_lds(x + c[v][k], &slab[wid][v * 4 + k][0]);
                }
            }
            // Phase 1b: stream sx (nt) — overlaps with gathers in flight.
            #pragma unroll
            for (int v = 0; v < ITEMS / 4; ++v) {
                s[v] = __builtin_nontemporal_load(
                           reinterpret_cast<const f32x4*>(sx + j0) + v);
            }
        }

        // Drain vmcnt (compiler emits s_waitcnt vmcnt(0) before s_barrier):
        // slab contents valid for all waves after this.
        __syncthreads();

        if (active) {
            // Phase 2: consume slab (conflict-free: all lanes same k, stride
            // 4B -> distinct banks), fused with row-walk accumulation.
            float sum = 0.0f;
            #pragma unroll
            for (int k = 0; k < ITEMS; ++k) {
                int jj = j0 + k;
                while (jj >= row_end) {          // handles empty rows
                    if (sum != 0.0f) atomicAdd(&y[lo + r_local], sum);
                    sum = 0.0f;
                    ++r_local;
                    row_end = sro[r_local + 1];
                }
                sum += slab[wid][k][lane] * s[k >> 2][k & 3];
            }
            if (sum != 0.0f) atomicAdd(&y[lo + r_local], sum);
        }
    } else if (active) {
        // Fallback (block row-range exceeded SRO_CAP; P ~ 0 for this data).
        int r       = row_of(ro, num_rows, j0);
        int row_end = ro[r + 1];
        float sum = 0.0f;
        for (int j = j0; j < min(nnz, j0 + ITEMS); ++j) {
            while (j >= row_end) {
                if (sum != 0.0f) atomicAdd(&y[r], sum);
                sum = 0.0f;
                ++r;
                row_end = ro[r + 1];
            }
            sum += sx[j] * x[sel[j]];
        }
        if (sum != 0.0f) atomicAdd(&y[r], sum);
    }
}

extern "C" void kernel_launch(void* const* d_in, const int* in_sizes, int n_in,
                              void* d_out, int out_size, void* d_ws, size_t ws_size,
                              hipStream_t stream) {
    const float* sx  = (const float*)d_in[0];
    const float* x   = (const float*)d_in[1];
    // d_in[2] is the zero "y" input — unused; we zero d_out ourselves.
    const int*   sel = (const int*)d_in[3];
    const int*   ro  = (const int*)d_in[4];
    float*       y   = (float*)d_out;

    const int nnz      = in_sizes[0];
    const int num_rows = in_sizes[4] - 1;   // == out_size

    {
        int threads = 256;
        int blocks  = (out_size + threads - 1) / threads;
        zero_out<<<blocks, threads, 0, stream>>>(y, out_size);
    }
    {
        int blocks = (nnz + CHUNK_NNZ - 1) / CHUNK_NNZ;
        spmv_chunk<<<blocks, BLOCK, 0, stream>>>(sx, x, sel, ro, y, nnz, num_rows);
    }
}